// Round 1
// baseline (9662.736 us; speedup 1.0000x reference)
//
#include <hip/hip_runtime.h>
#include <hip/hip_bf16.h>
#include <math.h>

#define MASK_ID (-100)
#define SEQ 1024
#define BATCH 4
#define DMODEL 768
#define NHEAD 12
#define DHEAD 64
#define NLAYER 10
#define HIDDEN 3072

// ---------------------------------------------------------------- temb+silu
__global__ void temb_silu_kernel(const int* __restrict__ t, float* __restrict__ stemb) {
    int b = blockIdx.x;
    int j = threadIdx.x;           // 0..383
    float tv = (float)t[b * SEQ];  // t broadcast along s
    float freq = expf(-logf(10000.f) * (float)j / 383.f);
    float arg = tv * freq;
    float s = sinf(arg), c = cosf(arg);
    stemb[b * DMODEL + j]       = s / (1.f + expf(-s));
    stemb[b * DMODEL + 384 + j] = c / (1.f + expf(-c));
}

// ---------------------------------------------------------------- adaln e-vectors
// slot: 2i = adaln1 layer i, 2i+1 = adaln2 layer i, 20 = nout
__global__ __launch_bounds__(256)
void adaln_e_kernel(const float* __restrict__ stemb,
                    const float* __restrict__ a1w, const float* __restrict__ a1b,
                    const float* __restrict__ a2w, const float* __restrict__ a2b,
                    const float* __restrict__ nw,  const float* __restrict__ nb,
                    float* __restrict__ e_all) {
    int chunk = blockIdx.x;   // 0..5
    int b     = blockIdx.y;   // 0..3
    int slot  = blockIdx.z;   // 0..20
    int col = chunk * 256 + threadIdx.x;   // 0..1535
    const float* W; const float* bb;
    if (slot == 20) { W = nw; bb = nb; }
    else {
        int i = slot >> 1;
        if (slot & 1) { W = a2w + (size_t)i * DMODEL * 2 * DMODEL; bb = a2b + i * 2 * DMODEL; }
        else          { W = a1w + (size_t)i * DMODEL * 2 * DMODEL; bb = a1b + i * 2 * DMODEL; }
    }
    const float* sb = stemb + b * DMODEL;
    float acc = bb[col];
    for (int k = 0; k < DMODEL; ++k)
        acc += sb[k] * W[(size_t)k * (2 * DMODEL) + col];
    e_all[((size_t)slot * BATCH + b) * (2 * DMODEL) + col] = acc;
}

// ---------------------------------------------------------------- fused LN + adaLN modulation
__global__ __launch_bounds__(256)
void ln_adaln_kernel(const float* __restrict__ in, float* __restrict__ out,
                     const float* __restrict__ g, const float* __restrict__ be,
                     const float* __restrict__ e) {
    int row = blockIdx.x;            // 0..4095
    int b = row >> 10;
    const float* xr = in + (size_t)row * DMODEL;
    int tid = threadIdx.x;
    float v0 = xr[tid], v1 = xr[tid + 256], v2 = xr[tid + 512];
    float s = v0 + v1 + v2;
    float ss = v0 * v0 + v1 * v1 + v2 * v2;
    #pragma unroll
    for (int o = 32; o; o >>= 1) { s += __shfl_down(s, o); ss += __shfl_down(ss, o); }
    __shared__ float ls[4], lss[4];
    __shared__ float mu_s, rs_s;
    int wid = tid >> 6, lane = tid & 63;
    if (lane == 0) { ls[wid] = s; lss[wid] = ss; }
    __syncthreads();
    if (tid == 0) {
        float S = ls[0] + ls[1] + ls[2] + ls[3];
        float SS = lss[0] + lss[1] + lss[2] + lss[3];
        float mu = S * (1.f / DMODEL);
        float var = SS * (1.f / DMODEL) - mu * mu;
        mu_s = mu;
        rs_s = rsqrtf(var + 1e-5f);
    }
    __syncthreads();
    float mu = mu_s, rs = rs_s;
    const float* esc = e + (size_t)b * (2 * DMODEL);
    float* orow = out + (size_t)row * DMODEL;
    #pragma unroll
    for (int j = 0; j < 3; ++j) {
        int c = tid + j * 256;
        float v = (j == 0) ? v0 : (j == 1) ? v1 : v2;
        float y = (v - mu) * rs * g[c] + be[c];
        y = y * (1.f + esc[c]) + esc[DMODEL + c];
        orow[c] = y;
    }
}

// ---------------------------------------------------------------- tiled fp32 GEMM
// EPI: 0 = bias, 1 = bias + pos-emb, 2 = bias + in-place residual (out += ...), 3 = bias + gelu
__device__ __forceinline__ float gelu_exact(float x) {
    return 0.5f * x * (1.f + erff(x * 0.70710678118654752f));
}

template<int EPI>
__global__ __launch_bounds__(256)
void gemm_f32(const float* __restrict__ A, const float* __restrict__ W,
              const float* __restrict__ bias, float* __restrict__ out,
              const float* __restrict__ emb_h, const float* __restrict__ emb_w,
              const int* __restrict__ tok,
              int M, int N, int K) {
    __shared__ float As[16][72];  // row stride 288B (16B aligned), padded vs bank conflicts
    __shared__ float Bs[16][72];
    int tid = threadIdx.x;
    int bx = blockIdx.x, by = blockIdx.y;
    int tx = tid & 15, ty = tid >> 4;
    int arow = tid >> 2, acol4 = (tid & 3) * 4;
    int brow = tid >> 4, bcol4 = (tid & 15) * 4;
    const float* Ab = A + (size_t)(by * 64 + arow) * K + acol4;
    const float* Wb = W + (size_t)brow * N + bx * 64 + bcol4;
    float acc[4][4] = {};
    int nk = K >> 4;
    for (int kt = 0; kt < nk; ++kt) {
        float4 a = *(const float4*)(Ab + kt * 16);
        float4 bv = *(const float4*)(Wb + (size_t)kt * 16 * N);
        As[acol4 + 0][arow] = a.x;
        As[acol4 + 1][arow] = a.y;
        As[acol4 + 2][arow] = a.z;
        As[acol4 + 3][arow] = a.w;
        *(float4*)&Bs[brow][bcol4] = bv;
        __syncthreads();
        #pragma unroll
        for (int k = 0; k < 16; ++k) {
            float4 av = *(const float4*)&As[k][ty * 4];
            float4 bw = *(const float4*)&Bs[k][tx * 4];
            float ar[4] = {av.x, av.y, av.z, av.w};
            float br[4] = {bw.x, bw.y, bw.z, bw.w};
            #pragma unroll
            for (int i = 0; i < 4; ++i)
                #pragma unroll
                for (int j = 0; j < 4; ++j)
                    acc[i][j] = fmaf(ar[i], br[j], acc[i][j]);
        }
        __syncthreads();
    }
    int row0 = by * 64 + ty * 4, col0 = bx * 64 + tx * 4;
    #pragma unroll
    for (int i = 0; i < 4; ++i) {
        int r = row0 + i;
        #pragma unroll
        for (int j = 0; j < 4; ++j) {
            int c = col0 + j;
            float v = acc[i][j] + bias[c];
            if (EPI == 1) {
                int p0 = tok[r * 3 + 1], p1 = tok[r * 3 + 2];
                v += emb_h[p0 * DMODEL + c] + emb_w[p1 * DMODEL + c];
            } else if (EPI == 2) {
                v += out[(size_t)r * N + c];
            } else if (EPI == 3) {
                v = gelu_exact(v);
            }
            out[(size_t)r * N + c] = v;
        }
    }
}

// ---------------------------------------------------------------- sparse local attention
// one thread = one (b, head, query); <=25 candidate keys at q + dh*16 + dw
__global__ __launch_bounds__(64)
void attn_kernel(const float* __restrict__ qkv, const int* __restrict__ tok,
                 float* __restrict__ o_out) {
    int qg = blockIdx.x, hh = blockIdx.y, b = blockIdx.z;
    int q = qg * 64 + threadIdx.x;
    int m = b * SEQ + q;
    float* orow = o_out + (size_t)m * DMODEL + hh * DHEAD;
    int sid = tok[m * 3];
    if (sid == MASK_ID) {
        #pragma unroll
        for (int i = 0; i < 16; ++i) *(float4*)(orow + i * 4) = float4{0.f, 0.f, 0.f, 0.f};
        return;
    }
    int qh = tok[m * 3 + 1], qw = tok[m * 3 + 2];
    const float* qp = qkv + (size_t)m * (3 * DMODEL) + hh * DHEAD;
    float4 qv[16];
    #pragma unroll
    for (int i = 0; i < 16; ++i) qv[i] = *(const float4*)(qp + i * 4);
    float4 ov[16];
    #pragma unroll
    for (int i = 0; i < 16; ++i) ov[i] = float4{0.f, 0.f, 0.f, 0.f};
    float mx = -1e30f, den = 0.f;
    for (int dh = -2; dh <= 2; ++dh) {
        for (int dw = -2; dw <= 2; ++dw) {
            int kq = q + dh * 16 + dw;
            if (kq < 0 || kq >= SEQ) continue;
            int km = b * SEQ + kq;
            if (tok[km * 3] != sid) continue;
            int kh2 = tok[km * 3 + 1], kw2 = tok[km * 3 + 2];
            int adh = kh2 - qh; if (adh < 0) adh = -adh;
            int adw = kw2 - qw; if (adw < 0) adw = -adw;
            if (adh > 2 || adw > 2) continue;
            const float* kp = qkv + (size_t)km * (3 * DMODEL) + DMODEL + hh * DHEAD;
            float dot = 0.f;
            #pragma unroll
            for (int i = 0; i < 16; ++i) {
                float4 kv = *(const float4*)(kp + i * 4);
                dot = fmaf(qv[i].x, kv.x, dot);
                dot = fmaf(qv[i].y, kv.y, dot);
                dot = fmaf(qv[i].z, kv.z, dot);
                dot = fmaf(qv[i].w, kv.w, dot);
            }
            float sc = dot * 0.125f;   // 1/sqrt(64)
            float nm = fmaxf(mx, sc);
            float c1 = expf(mx - nm);
            float c2 = expf(sc - nm);
            den = den * c1 + c2;
            const float* vp = qkv + (size_t)km * (3 * DMODEL) + 2 * DMODEL + hh * DHEAD;
            #pragma unroll
            for (int i = 0; i < 16; ++i) {
                float4 vv = *(const float4*)(vp + i * 4);
                ov[i].x = ov[i].x * c1 + c2 * vv.x;
                ov[i].y = ov[i].y * c1 + c2 * vv.y;
                ov[i].z = ov[i].z * c1 + c2 * vv.z;
                ov[i].w = ov[i].w * c1 + c2 * vv.w;
            }
            mx = nm;
        }
    }
    float inv = 1.f / den;
    #pragma unroll
    for (int i = 0; i < 16; ++i) {
        float4 t4 = ov[i];
        t4.x *= inv; t4.y *= inv; t4.z *= inv; t4.w *= inv;
        *(float4*)(orow + i * 4) = t4;
    }
}

// ---------------------------------------------------------------- launch
extern "C" void kernel_launch(void* const* d_in, const int* in_sizes, int n_in,
                              void* d_out, int out_size, void* d_ws, size_t ws_size,
                              hipStream_t stream) {
    const float* x_in      = (const float*)d_in[0];
    const int*   t         = (const int*)d_in[1];
    const int*   tok       = (const int*)d_in[2];
    const float* proj_in_w = (const float*)d_in[3];
    const float* proj_in_b = (const float*)d_in[4];
    const float* h_emb     = (const float*)d_in[5];
    const float* w_emb     = (const float*)d_in[6];
    const float* adaln1_w  = (const float*)d_in[7];
    const float* adaln1_b  = (const float*)d_in[8];
    const float* ln1_g     = (const float*)d_in[9];
    const float* ln1_b     = (const float*)d_in[10];
    const float* qkv_w     = (const float*)d_in[11];
    const float* qkv_b     = (const float*)d_in[12];
    const float* o_w       = (const float*)d_in[13];
    const float* o_b       = (const float*)d_in[14];
    const float* adaln2_w  = (const float*)d_in[15];
    const float* adaln2_b  = (const float*)d_in[16];
    const float* ln2_g     = (const float*)d_in[17];
    const float* ln2_b     = (const float*)d_in[18];
    const float* fc1_w     = (const float*)d_in[19];
    const float* fc1_b     = (const float*)d_in[20];
    const float* fc2_w     = (const float*)d_in[21];
    const float* fc2_b     = (const float*)d_in[22];
    const float* nout_w    = (const float*)d_in[23];
    const float* nout_b    = (const float*)d_in[24];
    const float* nout_g    = (const float*)d_in[25];
    const float* nout_beta = (const float*)d_in[26];

    float* ws = (float*)d_ws;
    const size_t NX = (size_t)BATCH * SEQ * DMODEL;       // 3,145,728
    float* h     = ws;                                     // LN out / attn out (reused)
    float* qkv   = ws + NX;                                // 9,437,184
    float* hid   = ws + NX + (size_t)BATCH * SEQ * 3 * DMODEL;   // 12,582,912
    float* stemb = hid + (size_t)BATCH * SEQ * HIDDEN;
    float* e_all = stemb + BATCH * DMODEL;                 // 21*4*1536
    float* x     = (float*)d_out;                          // activation lives in d_out

    const int M = BATCH * SEQ;   // 4096

    temb_silu_kernel<<<BATCH, 384, 0, stream>>>(t, stemb);
    adaln_e_kernel<<<dim3(6, BATCH, 2 * NLAYER + 1), 256, 0, stream>>>(
        stemb, adaln1_w, adaln1_b, adaln2_w, adaln2_b, nout_w, nout_b, e_all);

    // proj_in + positional embeddings
    gemm_f32<1><<<dim3(DMODEL / 64, M / 64), 256, 0, stream>>>(
        x_in, proj_in_w, proj_in_b, x, h_emb, w_emb, tok, M, DMODEL, DMODEL);

    for (int i = 0; i < NLAYER; ++i) {
        ln_adaln_kernel<<<M, 256, 0, stream>>>(
            x, h, ln1_g + i * DMODEL, ln1_b + i * DMODEL,
            e_all + (size_t)(2 * i) * BATCH * 2 * DMODEL);
        gemm_f32<0><<<dim3(3 * DMODEL / 64, M / 64), 256, 0, stream>>>(
            h, qkv_w + (size_t)i * DMODEL * 3 * DMODEL, qkv_b + i * 3 * DMODEL,
            qkv, nullptr, nullptr, nullptr, M, 3 * DMODEL, DMODEL);
        attn_kernel<<<dim3(SEQ / 64, NHEAD, BATCH), 64, 0, stream>>>(qkv, tok, h);
        gemm_f32<2><<<dim3(DMODEL / 64, M / 64), 256, 0, stream>>>(
            h, o_w + (size_t)i * DMODEL * DMODEL, o_b + i * DMODEL,
            x, nullptr, nullptr, nullptr, M, DMODEL, DMODEL);
        ln_adaln_kernel<<<M, 256, 0, stream>>>(
            x, h, ln2_g + i * DMODEL, ln2_b + i * DMODEL,
            e_all + (size_t)(2 * i + 1) * BATCH * 2 * DMODEL);
        gemm_f32<3><<<dim3(HIDDEN / 64, M / 64), 256, 0, stream>>>(
            h, fc1_w + (size_t)i * DMODEL * HIDDEN, fc1_b + i * HIDDEN,
            hid, nullptr, nullptr, nullptr, M, HIDDEN, DMODEL);
        gemm_f32<2><<<dim3(DMODEL / 64, M / 64), 256, 0, stream>>>(
            hid, fc2_w + (size_t)i * HIDDEN * DMODEL, fc2_b + i * DMODEL,
            x, nullptr, nullptr, nullptr, M, DMODEL, HIDDEN);
    }

    // final adaLN (in-place on d_out: block owns row, reads before writes)
    ln_adaln_kernel<<<M, 256, 0, stream>>>(
        x, x, nout_g, nout_beta, e_all + (size_t)(2 * NLAYER) * BATCH * 2 * DMODEL);
}

// Round 2
// 2749.733 us; speedup vs baseline: 3.5141x; 3.5141x over previous
//
#include <hip/hip_runtime.h>
#include <hip/hip_bf16.h>
#include <math.h>

#define MASK_ID (-100)
#define SEQ 1024
#define BATCH 4
#define DMODEL 768
#define NHEAD 12
#define DHEAD 64
#define NLAYER 10
#define HIDDEN 3072

typedef unsigned short ushort_t;
typedef unsigned int uint_t;

// ---------------------------------------------------------------- bf16 helpers
__device__ __forceinline__ ushort_t f2bf(float f) {
    uint_t u = __float_as_uint(f);
    u = u + 0x7fffu + ((u >> 16) & 1u);   // round-to-nearest-even
    return (ushort_t)(u >> 16);
}
__device__ __forceinline__ float bf2f(ushort_t u) {
    return __uint_as_float(((uint_t)u) << 16);
}

// async global->LDS, 16 bytes per lane
__device__ __forceinline__ void async_ld16(ushort_t* lds, const ushort_t* g) {
    __builtin_amdgcn_global_load_lds((__attribute__((address_space(1))) const void*)g,
                                     (__attribute__((address_space(3))) void*)lds, 16, 0, 0);
}

// ---------------------------------------------------------------- temb+silu
__global__ void temb_silu_kernel(const int* __restrict__ t, float* __restrict__ stemb) {
    int b = blockIdx.x;
    int j = threadIdx.x;           // 0..383
    float tv = (float)t[b * SEQ];
    float freq = expf(-logf(10000.f) * (float)j / 383.f);
    float arg = tv * freq;
    float s = sinf(arg), c = cosf(arg);
    stemb[b * DMODEL + j]       = s / (1.f + expf(-s));
    stemb[b * DMODEL + 384 + j] = c / (1.f + expf(-c));
}

// ---------------------------------------------------------------- adaln e-vectors (fp32, tiny)
__global__ __launch_bounds__(256)
void adaln_e_kernel(const float* __restrict__ stemb,
                    const float* __restrict__ a1w, const float* __restrict__ a1b,
                    const float* __restrict__ a2w, const float* __restrict__ a2b,
                    const float* __restrict__ nw,  const float* __restrict__ nb,
                    float* __restrict__ e_all) {
    int chunk = blockIdx.x;   // 0..5
    int b     = blockIdx.y;   // 0..3
    int slot  = blockIdx.z;   // 0..20
    int col = chunk * 256 + threadIdx.x;
    const float* W; const float* bb;
    if (slot == 20) { W = nw; bb = nb; }
    else {
        int i = slot >> 1;
        if (slot & 1) { W = a2w + (size_t)i * DMODEL * 2 * DMODEL; bb = a2b + i * 2 * DMODEL; }
        else          { W = a1w + (size_t)i * DMODEL * 2 * DMODEL; bb = a1b + i * 2 * DMODEL; }
    }
    const float* sb = stemb + b * DMODEL;
    float acc = bb[col];
    for (int k = 0; k < DMODEL; ++k)
        acc += sb[k] * W[(size_t)k * (2 * DMODEL) + col];
    e_all[((size_t)slot * BATCH + b) * (2 * DMODEL) + col] = acc;
}

// ---------------------------------------------------------------- weight fp32 [R][C] -> bf16 [C][R]
__global__ __launch_bounds__(256)
void transpose_bf16_kernel(const float* __restrict__ in, ushort_t* __restrict__ out,
                           int R, int C) {
    __shared__ float tile[32][33];
    int tx = threadIdx.x & 31, ty = threadIdx.x >> 5;
    int c0 = blockIdx.x * 32, r0 = blockIdx.y * 32;
    #pragma unroll
    for (int i = 0; i < 4; ++i)
        tile[ty + 8 * i][tx] = in[(size_t)(r0 + ty + 8 * i) * C + c0 + tx];
    __syncthreads();
    #pragma unroll
    for (int i = 0; i < 4; ++i)
        out[(size_t)(c0 + ty + 8 * i) * R + r0 + tx] = f2bf(tile[tx][ty + 8 * i]);
}

// ---------------------------------------------------------------- fp32 -> bf16 elementwise (8/thread)
__global__ __launch_bounds__(256)
void f32_to_bf16_kernel(const float* __restrict__ in, ushort_t* __restrict__ out, int n8) {
    int i = blockIdx.x * 256 + threadIdx.x;
    if (i >= n8) return;
    float4 a = ((const float4*)in)[2 * i];
    float4 b = ((const float4*)in)[2 * i + 1];
    uint4 o;
    o.x = (uint_t)f2bf(a.x) | ((uint_t)f2bf(a.y) << 16);
    o.y = (uint_t)f2bf(a.z) | ((uint_t)f2bf(a.w) << 16);
    o.z = (uint_t)f2bf(b.x) | ((uint_t)f2bf(b.y) << 16);
    o.w = (uint_t)f2bf(b.z) | ((uint_t)f2bf(b.w) << 16);
    ((uint4*)out)[i] = o;
}

// ---------------------------------------------------------------- fused LN + adaLN modulation
// OUT_BF: 1 -> bf16 out, 0 -> fp32 out
template<int OUT_BF>
__global__ __launch_bounds__(256)
void ln_adaln_kernel(const float* __restrict__ in, void* __restrict__ outv,
                     const float* __restrict__ g, const float* __restrict__ be,
                     const float* __restrict__ e) {
    int row = blockIdx.x;
    int b = row >> 10;
    const float* xr = in + (size_t)row * DMODEL;
    int tid = threadIdx.x;
    float v0 = xr[tid], v1 = xr[tid + 256], v2 = xr[tid + 512];
    float s = v0 + v1 + v2;
    float ss = v0 * v0 + v1 * v1 + v2 * v2;
    #pragma unroll
    for (int o = 32; o; o >>= 1) { s += __shfl_down(s, o); ss += __shfl_down(ss, o); }
    __shared__ float ls[4], lss[4];
    __shared__ float mu_s, rs_s;
    int wid = tid >> 6, lane = tid & 63;
    if (lane == 0) { ls[wid] = s; lss[wid] = ss; }
    __syncthreads();
    if (tid == 0) {
        float S = ls[0] + ls[1] + ls[2] + ls[3];
        float SS = lss[0] + lss[1] + lss[2] + lss[3];
        float mu = S * (1.f / DMODEL);
        float var = SS * (1.f / DMODEL) - mu * mu;
        mu_s = mu;
        rs_s = rsqrtf(var + 1e-5f);
    }
    __syncthreads();
    float mu = mu_s, rs = rs_s;
    const float* esc = e + (size_t)b * (2 * DMODEL);
    #pragma unroll
    for (int j = 0; j < 3; ++j) {
        int c = tid + j * 256;
        float v = (j == 0) ? v0 : (j == 1) ? v1 : v2;
        float y = (v - mu) * rs * g[c] + be[c];
        y = y * (1.f + esc[c]) + esc[DMODEL + c];
        if (OUT_BF) ((ushort_t*)outv)[(size_t)row * DMODEL + c] = f2bf(y);
        else        ((float*)outv)[(size_t)row * DMODEL + c] = y;
    }
}

// ---------------------------------------------------------------- bf16 MFMA GEMM
// A: [M][K] bf16 row-major.  Wt: [N][K] bf16 row-major (transposed weight).
// EPI: 0 = bf16 out = acc+bias          (qkv)
//      1 = fp32 out = acc+bias+pos_emb  (proj_in)
//      2 = fp32 out += acc+bias         (o-proj, fc2: residual into x)
//      3 = bf16 out = gelu(acc+bias)    (fc1)
__device__ __forceinline__ float gelu_exact(float x) {
    return 0.5f * x * (1.f + erff(x * 0.70710678118654752f));
}

template<int BM, int BN, int EPI>
__global__ __launch_bounds__(256)
void gemm_bf16(const ushort_t* __restrict__ A, const ushort_t* __restrict__ Wt,
               const float* __restrict__ bias, void* __restrict__ outv,
               const float* __restrict__ emb_h, const float* __restrict__ emb_w,
               const int* __restrict__ tok,
               int M, int N, int K) {
    constexpr int FM = 4;          // 64 rows / wave
    constexpr int WN = BN / 2;     // wave col extent
    constexpr int FN = WN / 16;
    using f32x4  = __attribute__((ext_vector_type(4))) float;
    using bf16x8 = __attribute__((ext_vector_type(8))) short;

    __shared__ __align__(16) ushort_t As[BM * 64];
    __shared__ __align__(16) ushort_t Bs[BN * 64];

    int tid = threadIdx.x;
    int lane = tid & 63, wid = tid >> 6;
    int wr = wid >> 1, wc = wid & 1;
    int l16 = lane & 15, lg = lane >> 4;
    int bm0 = blockIdx.y * BM, bn0 = blockIdx.x * BN;

    f32x4 acc[FM][FN];
    #pragma unroll
    for (int m = 0; m < FM; ++m)
        #pragma unroll
        for (int n = 0; n < FN; ++n)
            #pragma unroll
            for (int r = 0; r < 4; ++r) acc[m][n][r] = 0.f;

    int nk = K >> 6;
    for (int kt = 0; kt < nk; ++kt) {
        // stage A: BM*8 chunks of 16B; B: BN*8 chunks
        #pragma unroll
        for (int s2 = 0; s2 < BM / 32; ++s2) {
            int ca = s2 * 256 + tid;
            int row = ca >> 3, kc = ca & 7;
            async_ld16(&As[ca * 8], A + (size_t)(bm0 + row) * K + kt * 64 + kc * 8);
        }
        #pragma unroll
        for (int s2 = 0; s2 < BN / 32; ++s2) {
            int ca = s2 * 256 + tid;
            int row = ca >> 3, kc = ca & 7;
            async_ld16(&Bs[ca * 8], Wt + (size_t)(bn0 + row) * K + kt * 64 + kc * 8);
        }
        asm volatile("s_waitcnt vmcnt(0)" ::: "memory");
        __syncthreads();
        #pragma unroll
        for (int kk = 0; kk < 2; ++kk) {
            bf16x8 af[FM], bfr[FN];
            #pragma unroll
            for (int m = 0; m < FM; ++m)
                af[m] = *(const bf16x8*)&As[(wr * 64 + m * 16 + l16) * 64 + kk * 32 + lg * 8];
            #pragma unroll
            for (int n = 0; n < FN; ++n)
                bfr[n] = *(const bf16x8*)&Bs[(wc * WN + n * 16 + l16) * 64 + kk * 32 + lg * 8];
            #pragma unroll
            for (int m = 0; m < FM; ++m)
                #pragma unroll
                for (int n = 0; n < FN; ++n)
                    acc[m][n] = __builtin_amdgcn_mfma_f32_16x16x32_bf16(af[m], bfr[n], acc[m][n], 0, 0, 0);
        }
        __syncthreads();
    }

    // epilogue: C/D layout col = lane&15, row = (lane>>4)*4 + r
    int r0 = bm0 + wr * 64, c0 = bn0 + wc * WN;
    #pragma unroll
    for (int m = 0; m < FM; ++m) {
        #pragma unroll
        for (int n = 0; n < FN; ++n) {
            int cc = c0 + n * 16 + l16;
            float bcol = bias[cc];
            #pragma unroll
            for (int r = 0; r < 4; ++r) {
                int row = r0 + m * 16 + lg * 4 + r;
                float v = acc[m][n][r] + bcol;
                if (EPI == 0) {
                    ((ushort_t*)outv)[(size_t)row * N + cc] = f2bf(v);
                } else if (EPI == 1) {
                    int p0 = tok[row * 3 + 1], p1 = tok[row * 3 + 2];
                    v += emb_h[p0 * DMODEL + cc] + emb_w[p1 * DMODEL + cc];
                    ((float*)outv)[(size_t)row * N + cc] = v;
                } else if (EPI == 2) {
                    float* op = (float*)outv + (size_t)row * N + cc;
                    *op = *op + v;
                } else {
                    ((ushort_t*)outv)[(size_t)row * N + cc] = f2bf(gelu_exact(v));
                }
            }
        }
    }
}

// ---------------------------------------------------------------- sparse local attention (bf16 in/out)
__global__ __launch_bounds__(64)
void attn_kernel(const ushort_t* __restrict__ qkv, const int* __restrict__ tok,
                 ushort_t* __restrict__ o_out) {
    int qg = blockIdx.x, hh = blockIdx.y, b = blockIdx.z;
    int q = qg * 64 + threadIdx.x;
    int m = b * SEQ + q;
    ushort_t* orow = o_out + (size_t)m * DMODEL + hh * DHEAD;
    int sid = tok[m * 3];
    if (sid == MASK_ID) {
        uint4 z = {0u, 0u, 0u, 0u};
        #pragma unroll
        for (int i = 0; i < 8; ++i) ((uint4*)orow)[i] = z;
        return;
    }
    int qh = tok[m * 3 + 1], qw = tok[m * 3 + 2];
    const ushort_t* qp = qkv + (size_t)m * (3 * DMODEL) + hh * DHEAD;
    float qv[64], ov[64];
    #pragma unroll
    for (int i = 0; i < 8; ++i) {
        uint4 u = ((const uint4*)qp)[i];
        qv[i * 8 + 0] = bf2f(u.x & 0xffff); qv[i * 8 + 1] = bf2f(u.x >> 16);
        qv[i * 8 + 2] = bf2f(u.y & 0xffff); qv[i * 8 + 3] = bf2f(u.y >> 16);
        qv[i * 8 + 4] = bf2f(u.z & 0xffff); qv[i * 8 + 5] = bf2f(u.z >> 16);
        qv[i * 8 + 6] = bf2f(u.w & 0xffff); qv[i * 8 + 7] = bf2f(u.w >> 16);
    }
    #pragma unroll
    for (int i = 0; i < 64; ++i) ov[i] = 0.f;
    float mx = -1e30f, den = 0.f;
    for (int dh = -2; dh <= 2; ++dh) {
        for (int dw = -2; dw <= 2; ++dw) {
            int kq = q + dh * 16 + dw;
            if (kq < 0 || kq >= SEQ) continue;
            int km = b * SEQ + kq;
            if (tok[km * 3] != sid) continue;
            int kh2 = tok[km * 3 + 1], kw2 = tok[km * 3 + 2];
            int adh = kh2 - qh; if (adh < 0) adh = -adh;
            int adw = kw2 - qw; if (adw < 0) adw = -adw;
            if (adh > 2 || adw > 2) continue;
            const ushort_t* kp = qkv + (size_t)km * (3 * DMODEL) + DMODEL + hh * DHEAD;
            float dot = 0.f;
            #pragma unroll
            for (int i = 0; i < 8; ++i) {
                uint4 u = ((const uint4*)kp)[i];
                dot = fmaf(qv[i * 8 + 0], bf2f(u.x & 0xffff), dot);
                dot = fmaf(qv[i * 8 + 1], bf2f(u.x >> 16), dot);
                dot = fmaf(qv[i * 8 + 2], bf2f(u.y & 0xffff), dot);
                dot = fmaf(qv[i * 8 + 3], bf2f(u.y >> 16), dot);
                dot = fmaf(qv[i * 8 + 4], bf2f(u.z & 0xffff), dot);
                dot = fmaf(qv[i * 8 + 5], bf2f(u.z >> 16), dot);
                dot = fmaf(qv[i * 8 + 6], bf2f(u.w & 0xffff), dot);
                dot = fmaf(qv[i * 8 + 7], bf2f(u.w >> 16), dot);
            }
            float sc = dot * 0.125f;
            float nm = fmaxf(mx, sc);
            float c1 = expf(mx - nm);
            float c2 = expf(sc - nm);
            den = den * c1 + c2;
            const ushort_t* vp = qkv + (size_t)km * (3 * DMODEL) + 2 * DMODEL + hh * DHEAD;
            #pragma unroll
            for (int i = 0; i < 8; ++i) {
                uint4 u = ((const uint4*)vp)[i];
                ov[i * 8 + 0] = ov[i * 8 + 0] * c1 + c2 * bf2f(u.x & 0xffff);
                ov[i * 8 + 1] = ov[i * 8 + 1] * c1 + c2 * bf2f(u.x >> 16);
                ov[i * 8 + 2] = ov[i * 8 + 2] * c1 + c2 * bf2f(u.y & 0xffff);
                ov[i * 8 + 3] = ov[i * 8 + 3] * c1 + c2 * bf2f(u.y >> 16);
                ov[i * 8 + 4] = ov[i * 8 + 4] * c1 + c2 * bf2f(u.z & 0xffff);
                ov[i * 8 + 5] = ov[i * 8 + 5] * c1 + c2 * bf2f(u.z >> 16);
                ov[i * 8 + 6] = ov[i * 8 + 6] * c1 + c2 * bf2f(u.w & 0xffff);
                ov[i * 8 + 7] = ov[i * 8 + 7] * c1 + c2 * bf2f(u.w >> 16);
            }
            mx = nm;
        }
    }
    float inv = 1.f / den;
    #pragma unroll
    for (int i = 0; i < 8; ++i) {
        uint4 o;
        o.x = (uint_t)f2bf(ov[i * 8 + 0] * inv) | ((uint_t)f2bf(ov[i * 8 + 1] * inv) << 16);
        o.y = (uint_t)f2bf(ov[i * 8 + 2] * inv) | ((uint_t)f2bf(ov[i * 8 + 3] * inv) << 16);
        o.z = (uint_t)f2bf(ov[i * 8 + 4] * inv) | ((uint_t)f2bf(ov[i * 8 + 5] * inv) << 16);
        o.w = (uint_t)f2bf(ov[i * 8 + 6] * inv) | ((uint_t)f2bf(ov[i * 8 + 7] * inv) << 16);
        ((uint4*)orow)[i] = o;
    }
}

// ---------------------------------------------------------------- launch
extern "C" void kernel_launch(void* const* d_in, const int* in_sizes, int n_in,
                              void* d_out, int out_size, void* d_ws, size_t ws_size,
                              hipStream_t stream) {
    const float* x_in      = (const float*)d_in[0];
    const int*   t         = (const int*)d_in[1];
    const int*   tok       = (const int*)d_in[2];
    const float* proj_in_w = (const float*)d_in[3];
    const float* proj_in_b = (const float*)d_in[4];
    const float* h_emb     = (const float*)d_in[5];
    const float* w_emb     = (const float*)d_in[6];
    const float* adaln1_w  = (const float*)d_in[7];
    const float* adaln1_b  = (const float*)d_in[8];
    const float* ln1_g     = (const float*)d_in[9];
    const float* ln1_b     = (const float*)d_in[10];
    const float* qkv_w     = (const float*)d_in[11];
    const float* qkv_b     = (const float*)d_in[12];
    const float* o_w       = (const float*)d_in[13];
    const float* o_b       = (const float*)d_in[14];
    const float* adaln2_w  = (const float*)d_in[15];
    const float* adaln2_b  = (const float*)d_in[16];
    const float* ln2_g     = (const float*)d_in[17];
    const float* ln2_b     = (const float*)d_in[18];
    const float* fc1_w     = (const float*)d_in[19];
    const float* fc1_b     = (const float*)d_in[20];
    const float* fc2_w     = (const float*)d_in[21];
    const float* fc2_b     = (const float*)d_in[22];
    const float* nout_w    = (const float*)d_in[23];
    const float* nout_b    = (const float*)d_in[24];
    const float* nout_g    = (const float*)d_in[25];
    const float* nout_beta = (const float*)d_in[26];

    const int M = BATCH * SEQ;   // 4096

    float* stemb = (float*)d_ws;                        // 3072
    float* e_all = stemb + BATCH * DMODEL;              // 21*4*1536 = 129024
    ushort_t* h_bf   = (ushort_t*)(e_all + 21 * BATCH * 2 * DMODEL);
    ushort_t* qkv_bf = h_bf + (size_t)M * DMODEL;       // 4096*2304
    ushort_t* hid_bf = qkv_bf + (size_t)M * 3 * DMODEL; // 4096*3072
    ushort_t* qkvT   = hid_bf + (size_t)M * HIDDEN;     // 768*2304
    ushort_t* oT     = qkvT + DMODEL * 3 * DMODEL;      // 768*768
    ushort_t* fc1T   = oT + DMODEL * DMODEL;            // 3072*768
    ushort_t* fc2T   = fc1T + DMODEL * HIDDEN;          // 768*3072
    float* x = (float*)d_out;

    temb_silu_kernel<<<BATCH, 384, 0, stream>>>(t, stemb);
    adaln_e_kernel<<<dim3(6, BATCH, 2 * NLAYER + 1), 256, 0, stream>>>(
        stemb, adaln1_w, adaln1_b, adaln2_w, adaln2_b, nout_w, nout_b, e_all);

    // input -> bf16 (into h_bf), proj weight -> bf16^T (into oT slot, free until layer 0)
    f32_to_bf16_kernel<<<(M * DMODEL / 8 + 255) / 256, 256, 0, stream>>>(x_in, h_bf, M * DMODEL / 8);
    transpose_bf16_kernel<<<dim3(DMODEL / 32, DMODEL / 32), 256, 0, stream>>>(proj_in_w, oT, DMODEL, DMODEL);
    gemm_bf16<128, 64, 1><<<dim3(DMODEL / 64, M / 128), 256, 0, stream>>>(
        h_bf, oT, proj_in_b, x, h_emb, w_emb, tok, M, DMODEL, DMODEL);

    for (int i = 0; i < NLAYER; ++i) {
        transpose_bf16_kernel<<<dim3(3 * DMODEL / 32, DMODEL / 32), 256, 0, stream>>>(
            qkv_w + (size_t)i * DMODEL * 3 * DMODEL, qkvT, DMODEL, 3 * DMODEL);
        transpose_bf16_kernel<<<dim3(DMODEL / 32, DMODEL / 32), 256, 0, stream>>>(
            o_w + (size_t)i * DMODEL * DMODEL, oT, DMODEL, DMODEL);
        transpose_bf16_kernel<<<dim3(HIDDEN / 32, DMODEL / 32), 256, 0, stream>>>(
            fc1_w + (size_t)i * DMODEL * HIDDEN, fc1T, DMODEL, HIDDEN);
        transpose_bf16_kernel<<<dim3(DMODEL / 32, HIDDEN / 32), 256, 0, stream>>>(
            fc2_w + (size_t)i * HIDDEN * DMODEL, fc2T, HIDDEN, DMODEL);

        ln_adaln_kernel<1><<<M, 256, 0, stream>>>(
            x, h_bf, ln1_g + i * DMODEL, ln1_b + i * DMODEL,
            e_all + (size_t)(2 * i) * BATCH * 2 * DMODEL);
        gemm_bf16<128, 128, 0><<<dim3(3 * DMODEL / 128, M / 128), 256, 0, stream>>>(
            h_bf, qkvT, qkv_b + i * 3 * DMODEL, qkv_bf, nullptr, nullptr, nullptr, M, 3 * DMODEL, DMODEL);
        attn_kernel<<<dim3(SEQ / 64, NHEAD, BATCH), 64, 0, stream>>>(qkv_bf, tok, h_bf);
        gemm_bf16<128, 64, 2><<<dim3(DMODEL / 64, M / 128), 256, 0, stream>>>(
            h_bf, oT, o_b + i * DMODEL, x, nullptr, nullptr, nullptr, M, DMODEL, DMODEL);
        ln_adaln_kernel<1><<<M, 256, 0, stream>>>(
            x, h_bf, ln2_g + i * DMODEL, ln2_b + i * DMODEL,
            e_all + (size_t)(2 * i + 1) * BATCH * 2 * DMODEL);
        gemm_bf16<128, 128, 3><<<dim3(HIDDEN / 128, M / 128), 256, 0, stream>>>(
            h_bf, fc1T, fc1_b + i * HIDDEN, hid_bf, nullptr, nullptr, nullptr, M, HIDDEN, DMODEL);
        gemm_bf16<128, 64, 2><<<dim3(DMODEL / 64, M / 128), 256, 0, stream>>>(
            hid_bf, fc2T, fc2_b + i * DMODEL, x, nullptr, nullptr, nullptr, M, DMODEL, HIDDEN);
    }

    ln_adaln_kernel<0><<<M, 256, 0, stream>>>(
        x, x, nout_g, nout_beta, e_all + (size_t)(2 * NLAYER) * BATCH * 2 * DMODEL);
}

// Round 3
// 2411.602 us; speedup vs baseline: 4.0068x; 1.1402x over previous
//
#include <hip/hip_runtime.h>
#include <hip/hip_bf16.h>
#include <math.h>

#define MASK_ID (-100)
#define SEQ 1024
#define BATCH 4
#define DMODEL 768
#define NHEAD 12
#define DHEAD 64
#define NLAYER 10
#define HIDDEN 3072

typedef unsigned short ushort_t;
typedef unsigned int uint_t;

// ---------------------------------------------------------------- bf16 helpers
__device__ __forceinline__ ushort_t f2bf(float f) {
    uint_t u = __float_as_uint(f);
    u = u + 0x7fffu + ((u >> 16) & 1u);   // round-to-nearest-even
    return (ushort_t)(u >> 16);
}
__device__ __forceinline__ float bf2f(ushort_t u) {
    return __uint_as_float(((uint_t)u) << 16);
}

// async global->LDS, 16 bytes per lane
__device__ __forceinline__ void async_ld16(ushort_t* lds, const ushort_t* g) {
    __builtin_amdgcn_global_load_lds((__attribute__((address_space(1))) const void*)g,
                                     (__attribute__((address_space(3))) void*)lds, 16, 0, 0);
}

// ---------------------------------------------------------------- temb+silu
__global__ void temb_silu_kernel(const int* __restrict__ t, float* __restrict__ stemb) {
    int b = blockIdx.x;
    int j = threadIdx.x;           // 0..383
    float tv = (float)t[b * SEQ];
    float freq = expf(-logf(10000.f) * (float)j / 383.f);
    float arg = tv * freq;
    float s = sinf(arg), c = cosf(arg);
    stemb[b * DMODEL + j]       = s / (1.f + expf(-s));
    stemb[b * DMODEL + 384 + j] = c / (1.f + expf(-c));
}

// ---------------------------------------------------------------- adaln e-vectors, stage 1
// grid (6 col-chunks, 8 k-splits, 21 slots); each W element read exactly once,
// amortized over the 4 batches in registers.
__global__ __launch_bounds__(256)
void adaln_partial_kernel(const float* __restrict__ stemb,
                          const float* __restrict__ a1w,
                          const float* __restrict__ a2w,
                          const float* __restrict__ nw,
                          float* __restrict__ partial) {
    int chunk = blockIdx.x;   // 0..5
    int kc    = blockIdx.y;   // 0..7
    int slot  = blockIdx.z;   // 0..20
    int tid = threadIdx.x;
    int col = chunk * 256 + tid;
    const float* W;
    if (slot == 20) W = nw;
    else {
        int i = slot >> 1;
        W = ((slot & 1) ? a2w : a1w) + (size_t)i * DMODEL * 2 * DMODEL;
    }
    __shared__ float sb[4 * 96];
    for (int idx = tid; idx < 4 * 96; idx += 256) {
        int bb = idx / 96, kk = idx % 96;
        sb[idx] = stemb[bb * DMODEL + kc * 96 + kk];
    }
    __syncthreads();
    const float* Wp = W + (size_t)(kc * 96) * (2 * DMODEL) + col;
    float a0 = 0.f, a1 = 0.f, a2 = 0.f, a3 = 0.f;
    #pragma unroll 4
    for (int kk = 0; kk < 96; ++kk) {
        float w = Wp[(size_t)kk * (2 * DMODEL)];
        a0 = fmaf(sb[kk], w, a0);
        a1 = fmaf(sb[96 + kk], w, a1);
        a2 = fmaf(sb[192 + kk], w, a2);
        a3 = fmaf(sb[288 + kk], w, a3);
    }
    size_t base = ((size_t)(slot * 8 + kc) * 4) * (2 * DMODEL) + col;
    partial[base + 0 * 2 * DMODEL] = a0;
    partial[base + 1 * 2 * DMODEL] = a1;
    partial[base + 2 * 2 * DMODEL] = a2;
    partial[base + 3 * 2 * DMODEL] = a3;
}

// stage 2: reduce 8 k-splits + bias
__global__ __launch_bounds__(256)
void adaln_reduce_kernel(const float* __restrict__ partial,
                         const float* __restrict__ a1b, const float* __restrict__ a2b,
                         const float* __restrict__ nb,
                         float* __restrict__ e_all) {
    int chunk = blockIdx.x;   // 0..5
    int slot  = blockIdx.y;   // 0..20
    int col = chunk * 256 + threadIdx.x;
    const float* bb;
    if (slot == 20) bb = nb;
    else {
        int i = slot >> 1;
        bb = ((slot & 1) ? a2b : a1b) + i * 2 * DMODEL;
    }
    float bias = bb[col];
    float s0 = bias, s1 = bias, s2 = bias, s3 = bias;
    #pragma unroll
    for (int kc = 0; kc < 8; ++kc) {
        size_t base = ((size_t)(slot * 8 + kc) * 4) * (2 * DMODEL) + col;
        s0 += partial[base + 0 * 2 * DMODEL];
        s1 += partial[base + 1 * 2 * DMODEL];
        s2 += partial[base + 2 * 2 * DMODEL];
        s3 += partial[base + 3 * 2 * DMODEL];
    }
    size_t o = (size_t)slot * 4 * (2 * DMODEL) + col;
    e_all[o + 0 * 2 * DMODEL] = s0;
    e_all[o + 1 * 2 * DMODEL] = s1;
    e_all[o + 2 * 2 * DMODEL] = s2;
    e_all[o + 3 * 2 * DMODEL] = s3;
}

// ---------------------------------------------------------------- weight fp32 [R][C] -> bf16 [C][R]
__global__ __launch_bounds__(256)
void transpose_bf16_kernel(const float* __restrict__ in, ushort_t* __restrict__ out,
                           int R, int C) {
    __shared__ float tile[32][33];
    int tx = threadIdx.x & 31, ty = threadIdx.x >> 5;
    int c0 = blockIdx.x * 32, r0 = blockIdx.y * 32;
    #pragma unroll
    for (int i = 0; i < 4; ++i)
        tile[ty + 8 * i][tx] = in[(size_t)(r0 + ty + 8 * i) * C + c0 + tx];
    __syncthreads();
    #pragma unroll
    for (int i = 0; i < 4; ++i)
        out[(size_t)(c0 + ty + 8 * i) * R + r0 + tx] = f2bf(tile[tx][ty + 8 * i]);
}

// per-layer merged transpose of qkv_w / o_w / fc1_w / fc2_w (one launch)
__global__ __launch_bounds__(256)
void transpose4_bf16_kernel(const float* __restrict__ w0, const float* __restrict__ w1,
                            const float* __restrict__ w2, const float* __restrict__ w3,
                            ushort_t* __restrict__ o0, ushort_t* __restrict__ o1,
                            ushort_t* __restrict__ o2, ushort_t* __restrict__ o3) {
    int id = blockIdx.x;
    const float* in; ushort_t* out; int R, C, tile_id, TX;
    if (id < 1728)      { in = w0; out = o0; R = DMODEL; C = 3 * DMODEL; tile_id = id;        TX = 72; }
    else if (id < 2304) { in = w1; out = o1; R = DMODEL; C = DMODEL;     tile_id = id - 1728; TX = 24; }
    else if (id < 4608) { in = w2; out = o2; R = DMODEL; C = HIDDEN;     tile_id = id - 2304; TX = 96; }
    else                { in = w3; out = o3; R = HIDDEN; C = DMODEL;     tile_id = id - 4608; TX = 24; }
    int c0 = (tile_id % TX) * 32, r0 = (tile_id / TX) * 32;
    __shared__ float tile[32][33];
    int tx = threadIdx.x & 31, ty = threadIdx.x >> 5;
    #pragma unroll
    for (int i = 0; i < 4; ++i)
        tile[ty + 8 * i][tx] = in[(size_t)(r0 + ty + 8 * i) * C + c0 + tx];
    __syncthreads();
    #pragma unroll
    for (int i = 0; i < 4; ++i)
        out[(size_t)(c0 + ty + 8 * i) * R + r0 + tx] = f2bf(tile[tx][ty + 8 * i]);
}

// ---------------------------------------------------------------- fp32 -> bf16 elementwise (8/thread)
__global__ __launch_bounds__(256)
void f32_to_bf16_kernel(const float* __restrict__ in, ushort_t* __restrict__ out, int n8) {
    int i = blockIdx.x * 256 + threadIdx.x;
    if (i >= n8) return;
    float4 a = ((const float4*)in)[2 * i];
    float4 b = ((const float4*)in)[2 * i + 1];
    uint4 o;
    o.x = (uint_t)f2bf(a.x) | ((uint_t)f2bf(a.y) << 16);
    o.y = (uint_t)f2bf(a.z) | ((uint_t)f2bf(a.w) << 16);
    o.z = (uint_t)f2bf(b.x) | ((uint_t)f2bf(b.y) << 16);
    o.w = (uint_t)f2bf(b.z) | ((uint_t)f2bf(b.w) << 16);
    ((uint4*)out)[i] = o;
}

// ---------------------------------------------------------------- fused LN + adaLN modulation
template<int OUT_BF>
__global__ __launch_bounds__(256)
void ln_adaln_kernel(const float* __restrict__ in, void* __restrict__ outv,
                     const float* __restrict__ g, const float* __restrict__ be,
                     const float* __restrict__ e) {
    int row = blockIdx.x;
    int b = row >> 10;
    const float* xr = in + (size_t)row * DMODEL;
    int tid = threadIdx.x;
    float v0 = xr[tid], v1 = xr[tid + 256], v2 = xr[tid + 512];
    float s = v0 + v1 + v2;
    float ss = v0 * v0 + v1 * v1 + v2 * v2;
    #pragma unroll
    for (int o = 32; o; o >>= 1) { s += __shfl_down(s, o); ss += __shfl_down(ss, o); }
    __shared__ float ls[4], lss[4];
    __shared__ float mu_s, rs_s;
    int wid = tid >> 6, lane = tid & 63;
    if (lane == 0) { ls[wid] = s; lss[wid] = ss; }
    __syncthreads();
    if (tid == 0) {
        float S = ls[0] + ls[1] + ls[2] + ls[3];
        float SS = lss[0] + lss[1] + lss[2] + lss[3];
        float mu = S * (1.f / DMODEL);
        float var = SS * (1.f / DMODEL) - mu * mu;
        mu_s = mu;
        rs_s = rsqrtf(var + 1e-5f);
    }
    __syncthreads();
    float mu = mu_s, rs = rs_s;
    const float* esc = e + (size_t)b * (2 * DMODEL);
    #pragma unroll
    for (int j = 0; j < 3; ++j) {
        int c = tid + j * 256;
        float v = (j == 0) ? v0 : (j == 1) ? v1 : v2;
        float y = (v - mu) * rs * g[c] + be[c];
        y = y * (1.f + esc[c]) + esc[DMODEL + c];
        if (OUT_BF) ((ushort_t*)outv)[(size_t)row * DMODEL + c] = f2bf(y);
        else        ((float*)outv)[(size_t)row * DMODEL + c] = y;
    }
}

// ---------------------------------------------------------------- bf16 MFMA GEMM (unchanged from R1)
__device__ __forceinline__ float gelu_exact(float x) {
    return 0.5f * x * (1.f + erff(x * 0.70710678118654752f));
}

template<int BM, int BN, int EPI>
__global__ __launch_bounds__(256)
void gemm_bf16(const ushort_t* __restrict__ A, const ushort_t* __restrict__ Wt,
               const float* __restrict__ bias, void* __restrict__ outv,
               const float* __restrict__ emb_h, const float* __restrict__ emb_w,
               const int* __restrict__ tok,
               int M, int N, int K) {
    constexpr int FM = 4;
    constexpr int WN = BN / 2;
    constexpr int FN = WN / 16;
    using f32x4  = __attribute__((ext_vector_type(4))) float;
    using bf16x8 = __attribute__((ext_vector_type(8))) short;

    __shared__ __align__(16) ushort_t As[BM * 64];
    __shared__ __align__(16) ushort_t Bs[BN * 64];

    int tid = threadIdx.x;
    int lane = tid & 63, wid = tid >> 6;
    int wr = wid >> 1, wc = wid & 1;
    int l16 = lane & 15, lg = lane >> 4;
    int bm0 = blockIdx.y * BM, bn0 = blockIdx.x * BN;

    f32x4 acc[FM][FN];
    #pragma unroll
    for (int m = 0; m < FM; ++m)
        #pragma unroll
        for (int n = 0; n < FN; ++n)
            #pragma unroll
            for (int r = 0; r < 4; ++r) acc[m][n][r] = 0.f;

    int nk = K >> 6;
    for (int kt = 0; kt < nk; ++kt) {
        #pragma unroll
        for (int s2 = 0; s2 < BM / 32; ++s2) {
            int ca = s2 * 256 + tid;
            int row = ca >> 3, kc = ca & 7;
            async_ld16(&As[ca * 8], A + (size_t)(bm0 + row) * K + kt * 64 + kc * 8);
        }
        #pragma unroll
        for (int s2 = 0; s2 < BN / 32; ++s2) {
            int ca = s2 * 256 + tid;
            int row = ca >> 3, kc = ca & 7;
            async_ld16(&Bs[ca * 8], Wt + (size_t)(bn0 + row) * K + kt * 64 + kc * 8);
        }
        asm volatile("s_waitcnt vmcnt(0)" ::: "memory");
        __syncthreads();
        #pragma unroll
        for (int kk = 0; kk < 2; ++kk) {
            bf16x8 af[FM], bfr[FN];
            #pragma unroll
            for (int m = 0; m < FM; ++m)
                af[m] = *(const bf16x8*)&As[(wr * 64 + m * 16 + l16) * 64 + kk * 32 + lg * 8];
            #pragma unroll
            for (int n = 0; n < FN; ++n)
                bfr[n] = *(const bf16x8*)&Bs[(wc * WN + n * 16 + l16) * 64 + kk * 32 + lg * 8];
            #pragma unroll
            for (int m = 0; m < FM; ++m)
                #pragma unroll
                for (int n = 0; n < FN; ++n)
                    acc[m][n] = __builtin_amdgcn_mfma_f32_16x16x32_bf16(af[m], bfr[n], acc[m][n], 0, 0, 0);
        }
        __syncthreads();
    }

    int r0 = bm0 + wr * 64, c0 = bn0 + wc * WN;
    #pragma unroll
    for (int m = 0; m < FM; ++m) {
        #pragma unroll
        for (int n = 0; n < FN; ++n) {
            int cc = c0 + n * 16 + l16;
            float bcol = bias[cc];
            #pragma unroll
            for (int r = 0; r < 4; ++r) {
                int row = r0 + m * 16 + lg * 4 + r;
                float v = acc[m][n][r] + bcol;
                if (EPI == 0) {
                    ((ushort_t*)outv)[(size_t)row * N + cc] = f2bf(v);
                } else if (EPI == 1) {
                    int p0 = tok[row * 3 + 1], p1 = tok[row * 3 + 2];
                    v += emb_h[p0 * DMODEL + cc] + emb_w[p1 * DMODEL + cc];
                    ((float*)outv)[(size_t)row * N + cc] = v;
                } else if (EPI == 2) {
                    float* op = (float*)outv + (size_t)row * N + cc;
                    *op = *op + v;
                } else {
                    ((ushort_t*)outv)[(size_t)row * N + cc] = f2bf(gelu_exact(v));
                }
            }
        }
    }
}

// ---------------------------------------------------------------- sparse local attention
// 4 lanes per (q, head): lane part owns 16 dims. 256 thr / block, 12 waves/CU-class occupancy.
__global__ __launch_bounds__(256)
void attn_kernel(const ushort_t* __restrict__ qkv, const int* __restrict__ tok,
                 ushort_t* __restrict__ o_out) {
    int tid = threadIdx.x;
    int u = tid >> 2, part = tid & 3;
    int q = blockIdx.x * 16 + (u & 15);
    int h = blockIdx.y * 4 + (u >> 4);
    int b = blockIdx.z;
    int m = b * SEQ + q;
    ushort_t* op = o_out + (size_t)m * DMODEL + h * DHEAD + part * 16;
    int sid = tok[m * 3];
    if (sid == MASK_ID) {
        uint4 z = {0u, 0u, 0u, 0u};
        ((uint4*)op)[0] = z;
        ((uint4*)op)[1] = z;
        return;
    }
    int qh = tok[m * 3 + 1], qw = tok[m * 3 + 2];
    const ushort_t* qp = qkv + (size_t)m * (3 * DMODEL) + h * DHEAD + part * 16;
    float qv[16], ov[16];
    {
        uint4 u0 = ((const uint4*)qp)[0];
        uint4 u1 = ((const uint4*)qp)[1];
        qv[0] = bf2f(u0.x & 0xffff); qv[1] = bf2f(u0.x >> 16);
        qv[2] = bf2f(u0.y & 0xffff); qv[3] = bf2f(u0.y >> 16);
        qv[4] = bf2f(u0.z & 0xffff); qv[5] = bf2f(u0.z >> 16);
        qv[6] = bf2f(u0.w & 0xffff); qv[7] = bf2f(u0.w >> 16);
        qv[8]  = bf2f(u1.x & 0xffff); qv[9]  = bf2f(u1.x >> 16);
        qv[10] = bf2f(u1.y & 0xffff); qv[11] = bf2f(u1.y >> 16);
        qv[12] = bf2f(u1.z & 0xffff); qv[13] = bf2f(u1.z >> 16);
        qv[14] = bf2f(u1.w & 0xffff); qv[15] = bf2f(u1.w >> 16);
    }
    #pragma unroll
    for (int i = 0; i < 16; ++i) ov[i] = 0.f;
    float mx = -1e30f, den = 0.f;
    for (int dh = -2; dh <= 2; ++dh) {
        for (int dw = -2; dw <= 2; ++dw) {
            int kq = q + dh * 16 + dw;
            if (kq < 0 || kq >= SEQ) continue;
            int km = b * SEQ + kq;
            if (tok[km * 3] != sid) continue;
            int kh2 = tok[km * 3 + 1], kw2 = tok[km * 3 + 2];
            int adh = kh2 - qh; if (adh < 0) adh = -adh;
            int adw = kw2 - qw; if (adw < 0) adw = -adw;
            if (adh > 2 || adw > 2) continue;
            const ushort_t* kp = qkv + (size_t)km * (3 * DMODEL) + DMODEL + h * DHEAD + part * 16;
            float dot;
            {
                uint4 u0 = ((const uint4*)kp)[0];
                uint4 u1 = ((const uint4*)kp)[1];
                dot = qv[0] * bf2f(u0.x & 0xffff);
                dot = fmaf(qv[1], bf2f(u0.x >> 16), dot);
                dot = fmaf(qv[2], bf2f(u0.y & 0xffff), dot);
                dot = fmaf(qv[3], bf2f(u0.y >> 16), dot);
                dot = fmaf(qv[4], bf2f(u0.z & 0xffff), dot);
                dot = fmaf(qv[5], bf2f(u0.z >> 16), dot);
                dot = fmaf(qv[6], bf2f(u0.w & 0xffff), dot);
                dot = fmaf(qv[7], bf2f(u0.w >> 16), dot);
                dot = fmaf(qv[8],  bf2f(u1.x & 0xffff), dot);
                dot = fmaf(qv[9],  bf2f(u1.x >> 16), dot);
                dot = fmaf(qv[10], bf2f(u1.y & 0xffff), dot);
                dot = fmaf(qv[11], bf2f(u1.y >> 16), dot);
                dot = fmaf(qv[12], bf2f(u1.z & 0xffff), dot);
                dot = fmaf(qv[13], bf2f(u1.z >> 16), dot);
                dot = fmaf(qv[14], bf2f(u1.w & 0xffff), dot);
                dot = fmaf(qv[15], bf2f(u1.w >> 16), dot);
            }
            // combine partial dots across the 4 lanes of this quad
            dot += __shfl_xor(dot, 1);
            dot += __shfl_xor(dot, 2);
            float sc = dot * 0.125f;
            float nm = fmaxf(mx, sc);
            float c1 = expf(mx - nm);
            float c2 = expf(sc - nm);
            den = den * c1 + c2;
            const ushort_t* vp = qkv + (size_t)km * (3 * DMODEL) + 2 * DMODEL + h * DHEAD + part * 16;
            {
                uint4 u0 = ((const uint4*)vp)[0];
                uint4 u1 = ((const uint4*)vp)[1];
                ov[0] = ov[0] * c1 + c2 * bf2f(u0.x & 0xffff);
                ov[1] = ov[1] * c1 + c2 * bf2f(u0.x >> 16);
                ov[2] = ov[2] * c1 + c2 * bf2f(u0.y & 0xffff);
                ov[3] = ov[3] * c1 + c2 * bf2f(u0.y >> 16);
                ov[4] = ov[4] * c1 + c2 * bf2f(u0.z & 0xffff);
                ov[5] = ov[5] * c1 + c2 * bf2f(u0.z >> 16);
                ov[6] = ov[6] * c1 + c2 * bf2f(u0.w & 0xffff);
                ov[7] = ov[7] * c1 + c2 * bf2f(u0.w >> 16);
                ov[8]  = ov[8]  * c1 + c2 * bf2f(u1.x & 0xffff);
                ov[9]  = ov[9]  * c1 + c2 * bf2f(u1.x >> 16);
                ov[10] = ov[10] * c1 + c2 * bf2f(u1.y & 0xffff);
                ov[11] = ov[11] * c1 + c2 * bf2f(u1.y >> 16);
                ov[12] = ov[12] * c1 + c2 * bf2f(u1.z & 0xffff);
                ov[13] = ov[13] * c1 + c2 * bf2f(u1.z >> 16);
                ov[14] = ov[14] * c1 + c2 * bf2f(u1.w & 0xffff);
                ov[15] = ov[15] * c1 + c2 * bf2f(u1.w >> 16);
            }
            mx = nm;
        }
    }
    float inv = 1.f / den;
    uint4 o0, o1;
    o0.x = (uint_t)f2bf(ov[0] * inv) | ((uint_t)f2bf(ov[1] * inv) << 16);
    o0.y = (uint_t)f2bf(ov[2] * inv) | ((uint_t)f2bf(ov[3] * inv) << 16);
    o0.z = (uint_t)f2bf(ov[4] * inv) | ((uint_t)f2bf(ov[5] * inv) << 16);
    o0.w = (uint_t)f2bf(ov[6] * inv) | ((uint_t)f2bf(ov[7] * inv) << 16);
    o1.x = (uint_t)f2bf(ov[8]  * inv) | ((uint_t)f2bf(ov[9]  * inv) << 16);
    o1.y = (uint_t)f2bf(ov[10] * inv) | ((uint_t)f2bf(ov[11] * inv) << 16);
    o1.z = (uint_t)f2bf(ov[12] * inv) | ((uint_t)f2bf(ov[13] * inv) << 16);
    o1.w = (uint_t)f2bf(ov[14] * inv) | ((uint_t)f2bf(ov[15] * inv) << 16);
    ((uint4*)op)[0] = o0;
    ((uint4*)op)[1] = o1;
}

// ---------------------------------------------------------------- launch
extern "C" void kernel_launch(void* const* d_in, const int* in_sizes, int n_in,
                              void* d_out, int out_size, void* d_ws, size_t ws_size,
                              hipStream_t stream) {
    const float* x_in      = (const float*)d_in[0];
    const int*   t         = (const int*)d_in[1];
    const int*   tok       = (const int*)d_in[2];
    const float* proj_in_w = (const float*)d_in[3];
    const float* proj_in_b = (const float*)d_in[4];
    const float* h_emb     = (const float*)d_in[5];
    const float* w_emb     = (const float*)d_in[6];
    const float* adaln1_w  = (const float*)d_in[7];
    const float* adaln1_b  = (const float*)d_in[8];
    const float* ln1_g     = (const float*)d_in[9];
    const float* ln1_b     = (const float*)d_in[10];
    const float* qkv_w     = (const float*)d_in[11];
    const float* qkv_b     = (const float*)d_in[12];
    const float* o_w       = (const float*)d_in[13];
    const float* o_b       = (const float*)d_in[14];
    const float* adaln2_w  = (const float*)d_in[15];
    const float* adaln2_b  = (const float*)d_in[16];
    const float* ln2_g     = (const float*)d_in[17];
    const float* ln2_b     = (const float*)d_in[18];
    const float* fc1_w     = (const float*)d_in[19];
    const float* fc1_b     = (const float*)d_in[20];
    const float* fc2_w     = (const float*)d_in[21];
    const float* fc2_b     = (const float*)d_in[22];
    const float* nout_w    = (const float*)d_in[23];
    const float* nout_b    = (const float*)d_in[24];
    const float* nout_g    = (const float*)d_in[25];
    const float* nout_beta = (const float*)d_in[26];

    const int M = BATCH * SEQ;   // 4096

    float* stemb   = (float*)d_ws;                        // 3072
    float* e_all   = stemb + BATCH * DMODEL;              // 21*4*1536
    float* partial = e_all + 21 * BATCH * 2 * DMODEL;     // 21*8*4*1536
    ushort_t* h_bf   = (ushort_t*)(partial + 21 * 8 * 4 * 2 * DMODEL);
    ushort_t* qkv_bf = h_bf + (size_t)M * DMODEL;
    ushort_t* hid_bf = qkv_bf + (size_t)M * 3 * DMODEL;
    ushort_t* qkvT   = hid_bf + (size_t)M * HIDDEN;
    ushort_t* oT     = qkvT + DMODEL * 3 * DMODEL;
    ushort_t* fc1T   = oT + DMODEL * DMODEL;
    ushort_t* fc2T   = fc1T + DMODEL * HIDDEN;
    float* x = (float*)d_out;

    temb_silu_kernel<<<BATCH, 384, 0, stream>>>(t, stemb);
    adaln_partial_kernel<<<dim3(6, 8, 2 * NLAYER + 1), 256, 0, stream>>>(
        stemb, adaln1_w, adaln2_w, nout_w, partial);
    adaln_reduce_kernel<<<dim3(6, 2 * NLAYER + 1), 256, 0, stream>>>(
        partial, adaln1_b, adaln2_b, nout_b, e_all);

    f32_to_bf16_kernel<<<(M * DMODEL / 8 + 255) / 256, 256, 0, stream>>>(x_in, h_bf, M * DMODEL / 8);
    transpose_bf16_kernel<<<dim3(DMODEL / 32, DMODEL / 32), 256, 0, stream>>>(proj_in_w, oT, DMODEL, DMODEL);
    gemm_bf16<128, 64, 1><<<dim3(DMODEL / 64, M / 128), 256, 0, stream>>>(
        h_bf, oT, proj_in_b, x, h_emb, w_emb, tok, M, DMODEL, DMODEL);

    for (int i = 0; i < NLAYER; ++i) {
        transpose4_bf16_kernel<<<6912, 256, 0, stream>>>(
            qkv_w + (size_t)i * DMODEL * 3 * DMODEL,
            o_w + (size_t)i * DMODEL * DMODEL,
            fc1_w + (size_t)i * DMODEL * HIDDEN,
            fc2_w + (size_t)i * HIDDEN * DMODEL,
            qkvT, oT, fc1T, fc2T);

        ln_adaln_kernel<1><<<M, 256, 0, stream>>>(
            x, h_bf, ln1_g + i * DMODEL, ln1_b + i * DMODEL,
            e_all + (size_t)(2 * i) * BATCH * 2 * DMODEL);
        gemm_bf16<128, 128, 0><<<dim3(3 * DMODEL / 128, M / 128), 256, 0, stream>>>(
            h_bf, qkvT, qkv_b + i * 3 * DMODEL, qkv_bf, nullptr, nullptr, nullptr, M, 3 * DMODEL, DMODEL);
        attn_kernel<<<dim3(SEQ / 16, NHEAD / 4, BATCH), 256, 0, stream>>>(qkv_bf, tok, h_bf);
        gemm_bf16<128, 64, 2><<<dim3(DMODEL / 64, M / 128), 256, 0, stream>>>(
            h_bf, oT, o_b + i * DMODEL, x, nullptr, nullptr, nullptr, M, DMODEL, DMODEL);
        ln_adaln_kernel<1><<<M, 256, 0, stream>>>(
            x, h_bf, ln2_g + i * DMODEL, ln2_b + i * DMODEL,
            e_all + (size_t)(2 * i + 1) * BATCH * 2 * DMODEL);
        gemm_bf16<128, 128, 3><<<dim3(HIDDEN / 128, M / 128), 256, 0, stream>>>(
            h_bf, fc1T, fc1_b + i * HIDDEN, hid_bf, nullptr, nullptr, nullptr, M, HIDDEN, DMODEL);
        gemm_bf16<128, 64, 2><<<dim3(DMODEL / 64, M / 128), 256, 0, stream>>>(
            hid_bf, fc2T, fc2_b + i * DMODEL, x, nullptr, nullptr, nullptr, M, DMODEL, HIDDEN);
    }

    ln_adaln_kernel<0><<<M, 256, 0, stream>>>(
        x, x, nout_g, nout_beta, e_all + (size_t)(2 * NLAYER) * BATCH * 2 * DMODEL);
}

// Round 5
// 1875.712 us; speedup vs baseline: 5.1515x; 1.2857x over previous
//
#include <hip/hip_runtime.h>
#include <hip/hip_bf16.h>
#include <math.h>

#define MASK_ID (-100)
#define SEQ 1024
#define BATCH 4
#define DMODEL 768
#define NHEAD 12
#define DHEAD 64
#define NLAYER 10
#define HIDDEN 3072

typedef unsigned short ushort_t;
typedef unsigned int uint_t;

// ---------------------------------------------------------------- bf16 helpers
__device__ __forceinline__ ushort_t f2bf(float f) {
    uint_t u = __float_as_uint(f);
    u = u + 0x7fffu + ((u >> 16) & 1u);   // round-to-nearest-even
    return (ushort_t)(u >> 16);
}
__device__ __forceinline__ float bf2f(ushort_t u) {
    return __uint_as_float(((uint_t)u) << 16);
}

// async global->LDS, 16 bytes per lane
__device__ __forceinline__ void async_ld16(ushort_t* lds, const ushort_t* g) {
    __builtin_amdgcn_global_load_lds((__attribute__((address_space(1))) const void*)g,
                                     (__attribute__((address_space(3))) void*)lds, 16, 0, 0);
}

// ---------------------------------------------------------------- temb+silu
__global__ void temb_silu_kernel(const int* __restrict__ t, float* __restrict__ stemb) {
    int b = blockIdx.x;
    int j = threadIdx.x;           // 0..383
    float tv = (float)t[b * SEQ];
    float freq = expf(-logf(10000.f) * (float)j / 383.f);
    float arg = tv * freq;
    float s = sinf(arg), c = cosf(arg);
    stemb[b * DMODEL + j]       = s / (1.f + expf(-s));
    stemb[b * DMODEL + 384 + j] = c / (1.f + expf(-c));
}

// ---------------------------------------------------------------- adaln e-vectors, stage 1
__global__ __launch_bounds__(256)
void adaln_partial_kernel(const float* __restrict__ stemb,
                          const float* __restrict__ a1w,
                          const float* __restrict__ a2w,
                          const float* __restrict__ nw,
                          float* __restrict__ partial) {
    int chunk = blockIdx.x;   // 0..5
    int kc    = blockIdx.y;   // 0..7
    int slot  = blockIdx.z;   // 0..20
    int tid = threadIdx.x;
    int col = chunk * 256 + tid;
    const float* W;
    if (slot == 20) W = nw;
    else {
        int i = slot >> 1;
        W = ((slot & 1) ? a2w : a1w) + (size_t)i * DMODEL * 2 * DMODEL;
    }
    __shared__ float sb[4 * 96];
    for (int idx = tid; idx < 4 * 96; idx += 256) {
        int bb = idx / 96, kk = idx % 96;
        sb[idx] = stemb[bb * DMODEL + kc * 96 + kk];
    }
    __syncthreads();
    const float* Wp = W + (size_t)(kc * 96) * (2 * DMODEL) + col;
    float a0 = 0.f, a1 = 0.f, a2 = 0.f, a3 = 0.f;
    #pragma unroll 4
    for (int kk = 0; kk < 96; ++kk) {
        float w = Wp[(size_t)kk * (2 * DMODEL)];
        a0 = fmaf(sb[kk], w, a0);
        a1 = fmaf(sb[96 + kk], w, a1);
        a2 = fmaf(sb[192 + kk], w, a2);
        a3 = fmaf(sb[288 + kk], w, a3);
    }
    size_t base = ((size_t)(slot * 8 + kc) * 4) * (2 * DMODEL) + col;
    partial[base + 0 * 2 * DMODEL] = a0;
    partial[base + 1 * 2 * DMODEL] = a1;
    partial[base + 2 * 2 * DMODEL] = a2;
    partial[base + 3 * 2 * DMODEL] = a3;
}

__global__ __launch_bounds__(256)
void adaln_reduce_kernel(const float* __restrict__ partial,
                         const float* __restrict__ a1b, const float* __restrict__ a2b,
                         const float* __restrict__ nb,
                         float* __restrict__ e_all) {
    int chunk = blockIdx.x;   // 0..5
    int slot  = blockIdx.y;   // 0..20
    int col = chunk * 256 + threadIdx.x;
    const float* bb;
    if (slot == 20) bb = nb;
    else {
        int i = slot >> 1;
        bb = ((slot & 1) ? a2b : a1b) + i * 2 * DMODEL;
    }
    float bias = bb[col];
    float s0 = bias, s1 = bias, s2 = bias, s3 = bias;
    #pragma unroll
    for (int kc = 0; kc < 8; ++kc) {
        size_t base = ((size_t)(slot * 8 + kc) * 4) * (2 * DMODEL) + col;
        s0 += partial[base + 0 * 2 * DMODEL];
        s1 += partial[base + 1 * 2 * DMODEL];
        s2 += partial[base + 2 * 2 * DMODEL];
        s3 += partial[base + 3 * 2 * DMODEL];
    }
    size_t o = (size_t)slot * 4 * (2 * DMODEL) + col;
    e_all[o + 0 * 2 * DMODEL] = s0;
    e_all[o + 1 * 2 * DMODEL] = s1;
    e_all[o + 2 * 2 * DMODEL] = s2;
    e_all[o + 3 * 2 * DMODEL] = s3;
}

// ---------------------------------------------------------------- weight fp32 [R][C] -> bf16 [C][R]
__global__ __launch_bounds__(256)
void transpose_bf16_kernel(const float* __restrict__ in, ushort_t* __restrict__ out,
                           int R, int C) {
    __shared__ float tile[32][33];
    int tx = threadIdx.x & 31, ty = threadIdx.x >> 5;
    int c0 = blockIdx.x * 32, r0 = blockIdx.y * 32;
    #pragma unroll
    for (int i = 0; i < 4; ++i)
        tile[ty + 8 * i][tx] = in[(size_t)(r0 + ty + 8 * i) * C + c0 + tx];
    __syncthreads();
    #pragma unroll
    for (int i = 0; i < 4; ++i)
        out[(size_t)(c0 + ty + 8 * i) * R + r0 + tx] = f2bf(tile[tx][ty + 8 * i]);
}

__global__ __launch_bounds__(256)
void transpose4_bf16_kernel(const float* __restrict__ w0, const float* __restrict__ w1,
                            const float* __restrict__ w2, const float* __restrict__ w3,
                            ushort_t* __restrict__ o0, ushort_t* __restrict__ o1,
                            ushort_t* __restrict__ o2, ushort_t* __restrict__ o3) {
    int id = blockIdx.x;
    const float* in; ushort_t* out; int R, C, tile_id, TX;
    if (id < 1728)      { in = w0; out = o0; R = DMODEL; C = 3 * DMODEL; tile_id = id;        TX = 72; }
    else if (id < 2304) { in = w1; out = o1; R = DMODEL; C = DMODEL;     tile_id = id - 1728; TX = 24; }
    else if (id < 4608) { in = w2; out = o2; R = DMODEL; C = HIDDEN;     tile_id = id - 2304; TX = 96; }
    else                { in = w3; out = o3; R = HIDDEN; C = DMODEL;     tile_id = id - 4608; TX = 24; }
    int c0 = (tile_id % TX) * 32, r0 = (tile_id / TX) * 32;
    __shared__ float tile[32][33];
    int tx = threadIdx.x & 31, ty = threadIdx.x >> 5;
    #pragma unroll
    for (int i = 0; i < 4; ++i)
        tile[ty + 8 * i][tx] = in[(size_t)(r0 + ty + 8 * i) * C + c0 + tx];
    __syncthreads();
    #pragma unroll
    for (int i = 0; i < 4; ++i)
        out[(size_t)(c0 + ty + 8 * i) * R + r0 + tx] = f2bf(tile[tx][ty + 8 * i]);
}

// ---------------------------------------------------------------- fp32 -> bf16 elementwise (8/thread)
__global__ __launch_bounds__(256)
void f32_to_bf16_kernel(const float* __restrict__ in, ushort_t* __restrict__ out, int n8) {
    int i = blockIdx.x * 256 + threadIdx.x;
    if (i >= n8) return;
    float4 a = ((const float4*)in)[2 * i];
    float4 b = ((const float4*)in)[2 * i + 1];
    uint4 o;
    o.x = (uint_t)f2bf(a.x) | ((uint_t)f2bf(a.y) << 16);
    o.y = (uint_t)f2bf(a.z) | ((uint_t)f2bf(a.w) << 16);
    o.z = (uint_t)f2bf(b.x) | ((uint_t)f2bf(b.y) << 16);
    o.w = (uint_t)f2bf(b.z) | ((uint_t)f2bf(b.w) << 16);
    ((uint4*)out)[i] = o;
}

// ---------------------------------------------------------------- fused LN + adaLN modulation
template<int OUT_BF>
__global__ __launch_bounds__(256)
void ln_adaln_kernel(const float* __restrict__ in, void* __restrict__ outv,
                     const float* __restrict__ g, const float* __restrict__ be,
                     const float* __restrict__ e) {
    int row = blockIdx.x;
    int b = row >> 10;
    const float* xr = in + (size_t)row * DMODEL;
    int tid = threadIdx.x;
    float v0 = xr[tid], v1 = xr[tid + 256], v2 = xr[tid + 512];
    float s = v0 + v1 + v2;
    float ss = v0 * v0 + v1 * v1 + v2 * v2;
    #pragma unroll
    for (int o = 32; o; o >>= 1) { s += __shfl_down(s, o); ss += __shfl_down(ss, o); }
    __shared__ float ls[4], lss[4];
    __shared__ float mu_s, rs_s;
    int wid = tid >> 6, lane = tid & 63;
    if (lane == 0) { ls[wid] = s; lss[wid] = ss; }
    __syncthreads();
    if (tid == 0) {
        float S = ls[0] + ls[1] + ls[2] + ls[3];
        float SS = lss[0] + lss[1] + lss[2] + lss[3];
        float mu = S * (1.f / DMODEL);
        float var = SS * (1.f / DMODEL) - mu * mu;
        mu_s = mu;
        rs_s = rsqrtf(var + 1e-5f);
    }
    __syncthreads();
    float mu = mu_s, rs = rs_s;
    const float* esc = e + (size_t)b * (2 * DMODEL);
    #pragma unroll
    for (int j = 0; j < 3; ++j) {
        int c = tid + j * 256;
        float v = (j == 0) ? v0 : (j == 1) ? v1 : v2;
        float y = (v - mu) * rs * g[c] + be[c];
        y = y * (1.f + esc[c]) + esc[DMODEL + c];
        if (OUT_BF) ((ushort_t*)outv)[(size_t)row * DMODEL + c] = f2bf(y);
        else        ((float*)outv)[(size_t)row * DMODEL + c] = y;
    }
}

// ---------------------------------------------------------------- bf16 MFMA GEMM v2
// 2-phase double-buffered LDS (integer buffer offsets, no addrspace pointer arrays),
// XCD-swizzled 1D grid (nwg % 8 == 0 required), 4 waves as 2x2.
// EPI: 0 bf16 = acc+bias | 1 fp32 = acc+bias+pos_emb | 2 fp32 += acc+bias | 3 bf16 = gelu(acc+bias)
__device__ __forceinline__ float gelu_exact(float x) {
    return 0.5f * x * (1.f + erff(x * 0.70710678118654752f));
}

template<int BM, int BN, int EPI>
__global__ __launch_bounds__(256, 3)
void gemm_bf16(const ushort_t* __restrict__ A, const ushort_t* __restrict__ Wt,
               const float* __restrict__ bias, void* __restrict__ outv,
               const float* __restrict__ emb_h, const float* __restrict__ emb_w,
               const int* __restrict__ tok,
               int M, int N, int K) {
    constexpr int WM = BM / 2, WN = BN / 2;
    constexpr int FM = WM / 16, FN = WN / 16;
    constexpr int HALF = (BM + BN) * 64;   // elements per buffer (A tile + B tile)
    using f32x4  = __attribute__((ext_vector_type(4))) float;
    using bf16x8 = __attribute__((ext_vector_type(8))) short;

    __shared__ __align__(16) ushort_t lds[2 * HALF];

    int tid = threadIdx.x;
    int lane = tid & 63, wid = tid >> 6;
    int wr = wid >> 1, wc = wid & 1;
    int l16 = lane & 15, lg = lane >> 4;

    // XCD swizzle: blocks wg with wg%8==r (same XCD) get contiguous wgid chunk
    int nx = N / BN;
    int cpx = gridDim.x >> 3;
    int wg = blockIdx.x;
    int wgid = (wg & 7) * cpx + (wg >> 3);
    int bx = wgid % nx, by = wgid / nx;
    int bm0 = by * BM, bn0 = bx * BN;

    f32x4 acc[FM][FN];
    #pragma unroll
    for (int m = 0; m < FM; ++m)
        #pragma unroll
        for (int n = 0; n < FN; ++n)
            #pragma unroll
            for (int r = 0; r < 4; ++r) acc[m][n][r] = 0.f;

    const ushort_t* Abase = A + (size_t)bm0 * K;
    const ushort_t* Bbase = Wt + (size_t)bn0 * K;

    #define STAGE(bufoff, kt)                                                        \
        do {                                                                         \
            _Pragma("unroll")                                                        \
            for (int s2 = 0; s2 < BM / 32; ++s2) {                                   \
                int ca = s2 * 256 + tid;                                             \
                async_ld16(&lds[(bufoff) + ca * 8],                                  \
                           Abase + (size_t)(ca >> 3) * K + (kt) * 64 + (ca & 7) * 8);\
            }                                                                        \
            _Pragma("unroll")                                                        \
            for (int s2 = 0; s2 < BN / 32; ++s2) {                                   \
                int ca = s2 * 256 + tid;                                             \
                async_ld16(&lds[(bufoff) + BM * 64 + ca * 8],                        \
                           Bbase + (size_t)(ca >> 3) * K + (kt) * 64 + (ca & 7) * 8);\
            }                                                                        \
        } while (0)

    int nk = K >> 6;
    STAGE(0, 0);
    int curoff = 0;
    for (int kt = 0; kt < nk; ++kt) {
        asm volatile("s_waitcnt vmcnt(0)" ::: "memory");
        __syncthreads();
        if (kt + 1 < nk) STAGE(curoff ^ HALF, kt + 1);   // next-tile loads fly during compute
        #pragma unroll
        for (int kk = 0; kk < 2; ++kk) {
            bf16x8 af[FM], bfr[FN];
            #pragma unroll
            for (int m = 0; m < FM; ++m)
                af[m] = *(const bf16x8*)&lds[curoff + (wr * WM + m * 16 + l16) * 64 + kk * 32 + lg * 8];
            #pragma unroll
            for (int n = 0; n < FN; ++n)
                bfr[n] = *(const bf16x8*)&lds[curoff + BM * 64 + (wc * WN + n * 16 + l16) * 64 + kk * 32 + lg * 8];
            #pragma unroll
            for (int m = 0; m < FM; ++m)
                #pragma unroll
                for (int n = 0; n < FN; ++n)
                    acc[m][n] = __builtin_amdgcn_mfma_f32_16x16x32_bf16(af[m], bfr[n], acc[m][n], 0, 0, 0);
        }
        curoff ^= HALF;
    }
    #undef STAGE

    // epilogue: C/D layout col = lane&15, row = (lane>>4)*4 + r
    int r0 = bm0 + wr * WM, c0 = bn0 + wc * WN;
    #pragma unroll
    for (int m = 0; m < FM; ++m) {
        #pragma unroll
        for (int n = 0; n < FN; ++n) {
            int cc = c0 + n * 16 + l16;
            float bcol = bias[cc];
            #pragma unroll
            for (int r = 0; r < 4; ++r) {
                int row = r0 + m * 16 + lg * 4 + r;
                float v = acc[m][n][r] + bcol;
                if (EPI == 0) {
                    ((ushort_t*)outv)[(size_t)row * N + cc] = f2bf(v);
                } else if (EPI == 1) {
                    int p0 = tok[row * 3 + 1], p1 = tok[row * 3 + 2];
                    v += emb_h[p0 * DMODEL + cc] + emb_w[p1 * DMODEL + cc];
                    ((float*)outv)[(size_t)row * N + cc] = v;
                } else if (EPI == 2) {
                    float* op = (float*)outv + (size_t)row * N + cc;
                    *op = *op + v;
                } else {
                    ((ushort_t*)outv)[(size_t)row * N + cc] = f2bf(gelu_exact(v));
                }
            }
        }
    }
}

// ---------------------------------------------------------------- sparse local attention
// 4 lanes per (q, head): lane part owns 16 dims.
__global__ __launch_bounds__(256)
void attn_kernel(const ushort_t* __restrict__ qkv, const int* __restrict__ tok,
                 ushort_t* __restrict__ o_out) {
    int tid = threadIdx.x;
    int u = tid >> 2, part = tid & 3;
    int q = blockIdx.x * 16 + (u & 15);
    int h = blockIdx.y * 4 + (u >> 4);
    int b = blockIdx.z;
    int m = b * SEQ + q;
    ushort_t* op = o_out + (size_t)m * DMODEL + h * DHEAD + part * 16;
    int sid = tok[m * 3];
    if (sid == MASK_ID) {
        uint4 z = {0u, 0u, 0u, 0u};
        ((uint4*)op)[0] = z;
        ((uint4*)op)[1] = z;
        return;
    }
    int qh = tok[m * 3 + 1], qw = tok[m * 3 + 2];
    const ushort_t* qp = qkv + (size_t)m * (3 * DMODEL) + h * DHEAD + part * 16;
    float qv[16], ov[16];
    {
        uint4 u0 = ((const uint4*)qp)[0];
        uint4 u1 = ((const uint4*)qp)[1];
        qv[0] = bf2f(u0.x & 0xffff); qv[1] = bf2f(u0.x >> 16);
        qv[2] = bf2f(u0.y & 0xffff); qv[3] = bf2f(u0.y >> 16);
        qv[4] = bf2f(u0.z & 0xffff); qv[5] = bf2f(u0.z >> 16);
        qv[6] = bf2f(u0.w & 0xffff); qv[7] = bf2f(u0.w >> 16);
        qv[8]  = bf2f(u1.x & 0xffff); qv[9]  = bf2f(u1.x >> 16);
        qv[10] = bf2f(u1.y & 0xffff); qv[11] = bf2f(u1.y >> 16);
        qv[12] = bf2f(u1.z & 0xffff); qv[13] = bf2f(u1.z >> 16);
        qv[14] = bf2f(u1.w & 0xffff); qv[15] = bf2f(u1.w >> 16);
    }
    #pragma unroll
    for (int i = 0; i < 16; ++i) ov[i] = 0.f;
    float mx = -1e30f, den = 0.f;
    for (int dh = -2; dh <= 2; ++dh) {
        for (int dw = -2; dw <= 2; ++dw) {
            int kq = q + dh * 16 + dw;
            if (kq < 0 || kq >= SEQ) continue;
            int km = b * SEQ + kq;
            if (tok[km * 3] != sid) continue;
            int kh2 = tok[km * 3 + 1], kw2 = tok[km * 3 + 2];
            int adh = kh2 - qh; if (adh < 0) adh = -adh;
            int adw = kw2 - qw; if (adw < 0) adw = -adw;
            if (adh > 2 || adw > 2) continue;
            const ushort_t* kp = qkv + (size_t)km * (3 * DMODEL) + DMODEL + h * DHEAD + part * 16;
            float dot;
            {
                uint4 u0 = ((const uint4*)kp)[0];
                uint4 u1 = ((const uint4*)kp)[1];
                dot = qv[0] * bf2f(u0.x & 0xffff);
                dot = fmaf(qv[1], bf2f(u0.x >> 16), dot);
                dot = fmaf(qv[2], bf2f(u0.y & 0xffff), dot);
                dot = fmaf(qv[3], bf2f(u0.y >> 16), dot);
                dot = fmaf(qv[4], bf2f(u0.z & 0xffff), dot);
                dot = fmaf(qv[5], bf2f(u0.z >> 16), dot);
                dot = fmaf(qv[6], bf2f(u0.w & 0xffff), dot);
                dot = fmaf(qv[7], bf2f(u0.w >> 16), dot);
                dot = fmaf(qv[8],  bf2f(u1.x & 0xffff), dot);
                dot = fmaf(qv[9],  bf2f(u1.x >> 16), dot);
                dot = fmaf(qv[10], bf2f(u1.y & 0xffff), dot);
                dot = fmaf(qv[11], bf2f(u1.y >> 16), dot);
                dot = fmaf(qv[12], bf2f(u1.z & 0xffff), dot);
                dot = fmaf(qv[13], bf2f(u1.z >> 16), dot);
                dot = fmaf(qv[14], bf2f(u1.w & 0xffff), dot);
                dot = fmaf(qv[15], bf2f(u1.w >> 16), dot);
            }
            dot += __shfl_xor(dot, 1);
            dot += __shfl_xor(dot, 2);
            float sc = dot * 0.125f;
            float nm = fmaxf(mx, sc);
            float c1 = expf(mx - nm);
            float c2 = expf(sc - nm);
            den = den * c1 + c2;
            const ushort_t* vp = qkv + (size_t)km * (3 * DMODEL) + 2 * DMODEL + h * DHEAD + part * 16;
            {
                uint4 u0 = ((const uint4*)vp)[0];
                uint4 u1 = ((const uint4*)vp)[1];
                ov[0] = ov[0] * c1 + c2 * bf2f(u0.x & 0xffff);
                ov[1] = ov[1] * c1 + c2 * bf2f(u0.x >> 16);
                ov[2] = ov[2] * c1 + c2 * bf2f(u0.y & 0xffff);
                ov[3] = ov[3] * c1 + c2 * bf2f(u0.y >> 16);
                ov[4] = ov[4] * c1 + c2 * bf2f(u0.z & 0xffff);
                ov[5] = ov[5] * c1 + c2 * bf2f(u0.z >> 16);
                ov[6] = ov[6] * c1 + c2 * bf2f(u0.w & 0xffff);
                ov[7] = ov[7] * c1 + c2 * bf2f(u0.w >> 16);
                ov[8]  = ov[8]  * c1 + c2 * bf2f(u1.x & 0xffff);
                ov[9]  = ov[9]  * c1 + c2 * bf2f(u1.x >> 16);
                ov[10] = ov[10] * c1 + c2 * bf2f(u1.y & 0xffff);
                ov[11] = ov[11] * c1 + c2 * bf2f(u1.y >> 16);
                ov[12] = ov[12] * c1 + c2 * bf2f(u1.z & 0xffff);
                ov[13] = ov[13] * c1 + c2 * bf2f(u1.z >> 16);
                ov[14] = ov[14] * c1 + c2 * bf2f(u1.w & 0xffff);
                ov[15] = ov[15] * c1 + c2 * bf2f(u1.w >> 16);
            }
            mx = nm;
        }
    }
    float inv = 1.f / den;
    uint4 o0, o1;
    o0.x = (uint_t)f2bf(ov[0] * inv) | ((uint_t)f2bf(ov[1] * inv) << 16);
    o0.y = (uint_t)f2bf(ov[2] * inv) | ((uint_t)f2bf(ov[3] * inv) << 16);
    o0.z = (uint_t)f2bf(ov[4] * inv) | ((uint_t)f2bf(ov[5] * inv) << 16);
    o0.w = (uint_t)f2bf(ov[6] * inv) | ((uint_t)f2bf(ov[7] * inv) << 16);
    o1.x = (uint_t)f2bf(ov[8]  * inv) | ((uint_t)f2bf(ov[9]  * inv) << 16);
    o1.y = (uint_t)f2bf(ov[10] * inv) | ((uint_t)f2bf(ov[11] * inv) << 16);
    o1.z = (uint_t)f2bf(ov[12] * inv) | ((uint_t)f2bf(ov[13] * inv) << 16);
    o1.w = (uint_t)f2bf(ov[14] * inv) | ((uint_t)f2bf(ov[15] * inv) << 16);
    ((uint4*)op)[0] = o0;
    ((uint4*)op)[1] = o1;
}

// ---------------------------------------------------------------- launch
extern "C" void kernel_launch(void* const* d_in, const int* in_sizes, int n_in,
                              void* d_out, int out_size, void* d_ws, size_t ws_size,
                              hipStream_t stream) {
    const float* x_in      = (const float*)d_in[0];
    const int*   t         = (const int*)d_in[1];
    const int*   tok       = (const int*)d_in[2];
    const float* proj_in_w = (const float*)d_in[3];
    const float* proj_in_b = (const float*)d_in[4];
    const float* h_emb     = (const float*)d_in[5];
    const float* w_emb     = (const float*)d_in[6];
    const float* adaln1_w  = (const float*)d_in[7];
    const float* adaln1_b  = (const float*)d_in[8];
    const float* ln1_g     = (const float*)d_in[9];
    const float* ln1_b     = (const float*)d_in[10];
    const float* qkv_w     = (const float*)d_in[11];
    const float* qkv_b     = (const float*)d_in[12];
    const float* o_w       = (const float*)d_in[13];
    const float* o_b       = (const float*)d_in[14];
    const float* adaln2_w  = (const float*)d_in[15];
    const float* adaln2_b  = (const float*)d_in[16];
    const float* ln2_g     = (const float*)d_in[17];
    const float* ln2_b     = (const float*)d_in[18];
    const float* fc1_w     = (const float*)d_in[19];
    const float* fc1_b     = (const float*)d_in[20];
    const float* fc2_w     = (const float*)d_in[21];
    const float* fc2_b     = (const float*)d_in[22];
    const float* nout_w    = (const float*)d_in[23];
    const float* nout_b    = (const float*)d_in[24];
    const float* nout_g    = (const float*)d_in[25];
    const float* nout_beta = (const float*)d_in[26];

    const int M = BATCH * SEQ;   // 4096

    float* stemb   = (float*)d_ws;
    float* e_all   = stemb + BATCH * DMODEL;
    float* partial = e_all + 21 * BATCH * 2 * DMODEL;
    ushort_t* h_bf   = (ushort_t*)(partial + 21 * 8 * 4 * 2 * DMODEL);
    ushort_t* qkv_bf = h_bf + (size_t)M * DMODEL;
    ushort_t* hid_bf = qkv_bf + (size_t)M * 3 * DMODEL;
    ushort_t* qkvT   = hid_bf + (size_t)M * HIDDEN;
    ushort_t* oT     = qkvT + DMODEL * 3 * DMODEL;
    ushort_t* fc1T   = oT + DMODEL * DMODEL;
    ushort_t* fc2T   = fc1T + DMODEL * HIDDEN;
    float* x = (float*)d_out;

    temb_silu_kernel<<<BATCH, 384, 0, stream>>>(t, stemb);
    adaln_partial_kernel<<<dim3(6, 8, 2 * NLAYER + 1), 256, 0, stream>>>(
        stemb, adaln1_w, adaln2_w, nout_w, partial);
    adaln_reduce_kernel<<<dim3(6, 2 * NLAYER + 1), 256, 0, stream>>>(
        partial, adaln1_b, adaln2_b, nout_b, e_all);

    f32_to_bf16_kernel<<<(M * DMODEL / 8 + 255) / 256, 256, 0, stream>>>(x_in, h_bf, M * DMODEL / 8);
    transpose_bf16_kernel<<<dim3(DMODEL / 32, DMODEL / 32), 256, 0, stream>>>(proj_in_w, oT, DMODEL, DMODEL);
    // proj_in: grid (768/64)*(4096/64) = 768 blocks
    gemm_bf16<64, 64, 1><<<(DMODEL / 64) * (M / 64), 256, 0, stream>>>(
        h_bf, oT, proj_in_b, x, h_emb, w_emb, tok, M, DMODEL, DMODEL);

    for (int i = 0; i < NLAYER; ++i) {
        transpose4_bf16_kernel<<<6912, 256, 0, stream>>>(
            qkv_w + (size_t)i * DMODEL * 3 * DMODEL,
            o_w + (size_t)i * DMODEL * DMODEL,
            fc1_w + (size_t)i * DMODEL * HIDDEN,
            fc2_w + (size_t)i * HIDDEN * DMODEL,
            qkvT, oT, fc1T, fc2T);

        ln_adaln_kernel<1><<<M, 256, 0, stream>>>(
            x, h_bf, ln1_g + i * DMODEL, ln1_b + i * DMODEL,
            e_all + (size_t)(2 * i) * BATCH * 2 * DMODEL);
        // qkv: (2304/128)*(4096/64) = 18*64 = 1152 blocks
        gemm_bf16<64, 128, 0><<<(3 * DMODEL / 128) * (M / 64), 256, 0, stream>>>(
            h_bf, qkvT, qkv_b + i * 3 * DMODEL, qkv_bf, nullptr, nullptr, nullptr, M, 3 * DMODEL, DMODEL);
        attn_kernel<<<dim3(SEQ / 16, NHEAD / 4, BATCH), 256, 0, stream>>>(qkv_bf, tok, h_bf);
        // o-proj: 12*64 = 768 blocks
        gemm_bf16<64, 64, 2><<<(DMODEL / 64) * (M / 64), 256, 0, stream>>>(
            h_bf, oT, o_b + i * DMODEL, x, nullptr, nullptr, nullptr, M, DMODEL, DMODEL);
        ln_adaln_kernel<1><<<M, 256, 0, stream>>>(
            x, h_bf, ln2_g + i * DMODEL, ln2_b + i * DMODEL,
            e_all + (size_t)(2 * i + 1) * BATCH * 2 * DMODEL);
        // fc1: (3072/128)*(4096/64) = 24*64 = 1536 blocks
        gemm_bf16<64, 128, 3><<<(HIDDEN / 128) * (M / 64), 256, 0, stream>>>(
            h_bf, fc1T, fc1_b + i * HIDDEN, hid_bf, nullptr, nullptr, nullptr, M, HIDDEN, DMODEL);
        // fc2: 12*64 = 768 blocks
        gemm_bf16<64, 64, 2><<<(DMODEL / 64) * (M / 64), 256, 0, stream>>>(
            hid_bf, fc2T, fc2_b + i * DMODEL, x, nullptr, nullptr, nullptr, M, DMODEL, HIDDEN);
    }

    ln_adaln_kernel<0><<<M, 256, 0, stream>>>(
        x, x, nout_g, nout_beta, e_all + (size_t)(2 * NLAYER) * BATCH * 2 * DMODEL);
}